// Round 3
// baseline (4784.284 us; speedup 1.0000x reference)
//
#include <hip/hip_runtime.h>

// PILayer v2: latency-oriented rewrite.
//  - 2 edges per thread (e, e+128): every wave-uniform weight s_load feeds 2x FMAs,
//    and the two accumulator chains give in-thread ILP.
//  - gathers batched into register arrays (8 float4 in flight) before consumption.
//  - outputs staged in LDS (rotated slot to dodge bank conflicts) and flushed with
//    fully coalesced float4 stores: WRITE_SIZE 480MB -> ~105MB.
// Weights stay on the scalar path (wave-uniform indices -> s_load + v_fmac with SGPR).

constexpr int N_EDGES = 800000;
constexpr int H       = 32;    // channels / hidden
constexpr int DOUT    = 256;   // H * N_BASIS
constexpr int BLK     = 128;   // threads per block
constexpr int EPB     = 256;   // edges per block (2 per thread)

__device__ __forceinline__ float dot8(const float (&u)[8], const float4& b0, const float4& b1) {
    float a;
    a = u[0] * b0.x;
    a = fmaf(u[1], b0.y, a);
    a = fmaf(u[2], b0.z, a);
    a = fmaf(u[3], b0.w, a);
    a = fmaf(u[4], b1.x, a);
    a = fmaf(u[5], b1.y, a);
    a = fmaf(u[6], b1.z, a);
    a = fmaf(u[7], b1.w, a);
    return a;
}

// y1 += prop[node] @ Wpart   (32 input rows, 32 outputs). Loads all 8 float4 of the
// node row first (batched, vmcnt-staggered), then fully unrolled FMAs.
__device__ __forceinline__ void gemv_half(const float4* __restrict__ prop4, int node,
                                          const float* __restrict__ Wpart, float (&y1)[H]) {
    float4 x[8];
    #pragma unroll
    for (int q = 0; q < 8; ++q) x[q] = prop4[node * 8 + q];
    #pragma unroll
    for (int q = 0; q < 8; ++q) {
        const float* w = Wpart + (4 * q) * H;
        #pragma unroll
        for (int m = 0; m < H; ++m) {
            float a = y1[m];
            a = fmaf(x[q].x, w[0 * H + m], a);
            a = fmaf(x[q].y, w[1 * H + m], a);
            a = fmaf(x[q].z, w[2 * H + m], a);
            a = fmaf(x[q].w, w[3 * H + m], a);
            y1[m] = a;
        }
    }
}

// stages 1+2 for one edge -> y2
__device__ __forceinline__ void mlp12(const float4* __restrict__ prop4, int i, int j,
                                      const float* __restrict__ W1, const float* __restrict__ b1,
                                      const float* __restrict__ W2, const float* __restrict__ b2,
                                      float (&y2)[H]) {
    float y1[H];
    #pragma unroll
    for (int m = 0; m < H; ++m) y1[m] = b1[m];
    gemv_half(prop4, i, W1, y1);
    gemv_half(prop4, j, W1 + H * H, y1);   // rows 32..63

    #pragma unroll
    for (int m = 0; m < H; ++m) y2[m] = b2[m];
    #pragma unroll
    for (int k = 0; k < H; ++k) {
        const float yk = y1[k];
        const float* w = W2 + k * H;
        #pragma unroll
        for (int m = 0; m < H; ++m)
            y2[m] = fmaf(yk, w[m], y2[m]);
    }
}

__global__ __launch_bounds__(BLK, 3) void pilayer_f32_v2(
    const float* __restrict__ prop,
    const int*   __restrict__ idx_i,
    const int*   __restrict__ idx_j,
    const float* __restrict__ basis,
    const float* __restrict__ W1,
    const float* __restrict__ b1,
    const float* __restrict__ W2,
    const float* __restrict__ b2,
    const float* __restrict__ W3,
    float*       __restrict__ out)
{
    const int t  = threadIdx.x;
    const int eb = blockIdx.x * EPB;
    const int e0 = eb + t;            // edge set 0: [eb, eb+128)
    const int e1 = eb + BLK + t;      // edge set 1: [eb+128, eb+256)

    // output staging: [set][edge-local][hq] float4, hq slot rotated by edge-local row
    __shared__ float4 obuf[2][BLK][8];   // 32 KiB

    const float4* __restrict__ prop4  = reinterpret_cast<const float4*>(prop);
    const float4* __restrict__ basis4 = reinterpret_cast<const float4*>(basis);
    float4*       __restrict__ out4   = reinterpret_cast<float4*>(out);

    const int i0 = idx_i[e0], j0 = idx_j[e0];
    const int i1 = idx_i[e1], j1 = idx_j[e1];

    // ---------- stages 1+2 for both edges ----------
    float y2_0[H], y2_1[H];
    mlp12(prop4, i0, j0, W1, b1, W2, b2, y2_0);
    mlp12(prop4, i1, j1, W1, b1, W2, b2, y2_1);

    // basis loads issued here; first use is ~2k FMAs away (end of hq iteration 0)
    const float4 bs00 = basis4[e0 * 2 + 0], bs01 = basis4[e0 * 2 + 1];
    const float4 bs10 = basis4[e1 * 2 + 0], bs11 = basis4[e1 * 2 + 1];

    // ---------- stage 3: u[h][c] = sum_k y2[k] * W3[k, h*8+c]; out[h] = <u[h], basis> ----------
    #pragma unroll 1
    for (int hq = 0; hq < 8; ++hq) {
        float u0[4][8], u1[4][8];
        #pragma unroll
        for (int hh = 0; hh < 4; ++hh)
            #pragma unroll
            for (int c = 0; c < 8; ++c) { u0[hh][c] = 0.f; u1[hh][c] = 0.f; }

        const float* wbase = W3 + hq * 32;   // 128B slice per k-row
        #pragma unroll
        for (int k = 0; k < H; ++k) {
            const float* w = wbase + k * DOUT;
            const float a0 = y2_0[k];
            const float a1 = y2_1[k];
            #pragma unroll
            for (int hh = 0; hh < 4; ++hh) {
                #pragma unroll
                for (int c = 0; c < 8; ++c) {
                    const float wv = w[hh * 8 + c];
                    u0[hh][c] = fmaf(a0, wv, u0[hh][c]);
                    u1[hh][c] = fmaf(a1, wv, u1[hh][c]);
                }
            }
        }

        float4 r0, r1;
        r0.x = dot8(u0[0], bs00, bs01);
        r0.y = dot8(u0[1], bs00, bs01);
        r0.z = dot8(u0[2], bs00, bs01);
        r0.w = dot8(u0[3], bs00, bs01);
        r1.x = dot8(u1[0], bs10, bs11);
        r1.y = dot8(u1[1], bs10, bs11);
        r1.z = dot8(u1[2], bs10, bs11);
        r1.w = dot8(u1[3], bs10, bs11);

        obuf[0][t][(hq + t) & 7] = r0;   // rotated slot: conflict-free-ish write
        obuf[1][t][(hq + t) & 7] = r1;
    }

    __syncthreads();

    // ---------- coalesced flush: block's out4 range is [eb*8, eb*8 + 2048) ----------
    #pragma unroll
    for (int r = 0; r < 16; ++r) {
        const int g    = r * BLK + t;        // 0..2047, lane-consecutive
        const int s    = g >> 10;            // 0: edge set 0, 1: edge set 1
        const int gl   = g & 1023;
        const int eloc = gl >> 3;
        const int hq   = gl & 7;
        out4[eb * 8 + g] = obuf[s][eloc][(hq + eloc) & 7];
    }
}

extern "C" void kernel_launch(void* const* d_in, const int* in_sizes, int n_in,
                              void* d_out, int out_size, void* d_ws, size_t ws_size,
                              hipStream_t stream) {
    const float* prop  = (const float*)d_in[0];
    const int*   idx_i = (const int*)d_in[1];
    const int*   idx_j = (const int*)d_in[2];
    const float* basis = (const float*)d_in[3];
    const float* W1    = (const float*)d_in[4];
    const float* b1    = (const float*)d_in[5];
    const float* W2    = (const float*)d_in[6];
    const float* b2    = (const float*)d_in[7];
    const float* W3    = (const float*)d_in[8];
    float*       outp  = (float*)d_out;

    dim3 grid(N_EDGES / EPB);   // 3125 blocks, exact — no tail
    pilayer_f32_v2<<<grid, dim3(BLK), 0, stream>>>(prop, idx_i, idx_j, basis,
                                                   W1, b1, W2, b2, W3, outp);
}

// Round 5
// 452.720 us; speedup vs baseline: 10.5679x; 10.5679x over previous
//
#include <hip/hip_runtime.h>

// PILayer v3: v1 structure (1 edge/thread) with the three counter-isolated fixes:
//  1. __launch_bounds__(256,4): VGPR cap 128 so the ~110-live-reg body does NOT spill
//     (v1: VGPR=60 forced scratch spills; v2: 84 vs ~150 live = 11x disaster).
//  2. Both prop gathers (16 float4) issued back-to-back before any FMA.
//  3. Output staged in LDS (rotated slot) -> lane-consecutive float4 flush:
//     WRITE_SIZE 480MB -> ~105MB.
// Weights keep wave-uniform indices -> scalar s_load path (free vs VALU).

constexpr int N_EDGES = 800000;
constexpr int H       = 32;    // channels / hidden
constexpr int DOUT    = 256;   // H * N_BASIS
constexpr int BLK     = 256;   // threads per block == edges per block

__global__ __launch_bounds__(BLK, 4) void pilayer_f32_v3(
    const float* __restrict__ prop,
    const int*   __restrict__ idx_i,
    const int*   __restrict__ idx_j,
    const float* __restrict__ basis,
    const float* __restrict__ W1,
    const float* __restrict__ b1,
    const float* __restrict__ W2,
    const float* __restrict__ b2,
    const float* __restrict__ W3,
    float*       __restrict__ out)
{
    const int t  = threadIdx.x;
    const int eb = blockIdx.x * BLK;
    const int e  = eb + t;                     // grid exact: 3125*256 == 800000

    __shared__ float4 obuf[BLK][8];            // 32 KiB output staging

    const float4* __restrict__ prop4  = reinterpret_cast<const float4*>(prop);
    const float4* __restrict__ basis4 = reinterpret_cast<const float4*>(basis);
    float4*       __restrict__ out4   = reinterpret_cast<float4*>(out);

    const int i = idx_i[e];
    const int j = idx_j[e];

    // basis loads issued early; first use is ~3k FMAs away
    const float4 bs0 = basis4[e * 2 + 0];
    const float4 bs1 = basis4[e * 2 + 1];

    // ---------- all 16 gather loads in flight before any consumption ----------
    float4 xi[8], xj[8];
    #pragma unroll
    for (int q = 0; q < 8; ++q) xi[q] = prop4[i * 8 + q];
    #pragma unroll
    for (int q = 0; q < 8; ++q) xj[q] = prop4[j * 8 + q];

    // ---------- stage 1 : y1 = [xi ; xj] @ W1 + b1  (64->32) ----------
    float y1[H];
    #pragma unroll
    for (int m = 0; m < H; ++m) y1[m] = b1[m];

    #pragma unroll
    for (int q = 0; q < 8; ++q) {
        const float* w = W1 + (4 * q) * H;
        #pragma unroll
        for (int m = 0; m < H; ++m) {
            float a = y1[m];
            a = fmaf(xi[q].x, w[0 * H + m], a);
            a = fmaf(xi[q].y, w[1 * H + m], a);
            a = fmaf(xi[q].z, w[2 * H + m], a);
            a = fmaf(xi[q].w, w[3 * H + m], a);
            y1[m] = a;
        }
    }
    #pragma unroll
    for (int q = 0; q < 8; ++q) {
        const float* w = W1 + (32 + 4 * q) * H;
        #pragma unroll
        for (int m = 0; m < H; ++m) {
            float a = y1[m];
            a = fmaf(xj[q].x, w[0 * H + m], a);
            a = fmaf(xj[q].y, w[1 * H + m], a);
            a = fmaf(xj[q].z, w[2 * H + m], a);
            a = fmaf(xj[q].w, w[3 * H + m], a);
            y1[m] = a;
        }
    }

    // ---------- stage 2 : y2 = y1 @ W2 + b2  (32->32) ----------
    float y2[H];
    #pragma unroll
    for (int m = 0; m < H; ++m) y2[m] = b2[m];
    #pragma unroll
    for (int k = 0; k < H; ++k) {
        const float yk = y1[k];
        const float* w = W2 + k * H;
        #pragma unroll
        for (int m = 0; m < H; ++m)
            y2[m] = fmaf(yk, w[m], y2[m]);
    }

    // ---------- stage 3 : u[hh][c] = sum_k y2[k]*W3[k, hq*32+hh*8+c]; out = <u, basis> ----------
    #pragma unroll 1
    for (int hq = 0; hq < 8; ++hq) {
        float u[4][8];
        #pragma unroll
        for (int hh = 0; hh < 4; ++hh)
            #pragma unroll
            for (int c = 0; c < 8; ++c) u[hh][c] = 0.f;

        const float* wbase = W3 + hq * 32;     // 128B slice per k-row, wave-uniform
        #pragma unroll
        for (int k = 0; k < H; ++k) {
            const float yk = y2[k];
            const float* w = wbase + k * DOUT;
            #pragma unroll
            for (int hh = 0; hh < 4; ++hh) {
                #pragma unroll
                for (int c = 0; c < 8; ++c)
                    u[hh][c] = fmaf(yk, w[hh * 8 + c], u[hh][c]);
            }
        }

        float4 r;
        #pragma unroll
        for (int hh = 0; hh < 4; ++hh) {
            float a;
            a = u[hh][0] * bs0.x;
            a = fmaf(u[hh][1], bs0.y, a);
            a = fmaf(u[hh][2], bs0.z, a);
            a = fmaf(u[hh][3], bs0.w, a);
            a = fmaf(u[hh][4], bs1.x, a);
            a = fmaf(u[hh][5], bs1.y, a);
            a = fmaf(u[hh][6], bs1.z, a);
            a = fmaf(u[hh][7], bs1.w, a);
            (&r.x)[hh] = a;
        }

        obuf[t][(hq + t) & 7] = r;             // rotated slot: spreads banks
    }

    __syncthreads();

    // ---------- coalesced flush: block range out4[eb*8, eb*8+2048) ----------
    #pragma unroll
    for (int r8 = 0; r8 < 8; ++r8) {
        const int g    = r8 * BLK + t;         // 0..2047, lane-consecutive
        const int eloc = g >> 3;
        const int hq   = g & 7;
        out4[eb * 8 + g] = obuf[eloc][(hq + eloc) & 7];
    }
}

extern "C" void kernel_launch(void* const* d_in, const int* in_sizes, int n_in,
                              void* d_out, int out_size, void* d_ws, size_t ws_size,
                              hipStream_t stream) {
    const float* prop  = (const float*)d_in[0];
    const int*   idx_i = (const int*)d_in[1];
    const int*   idx_j = (const int*)d_in[2];
    const float* basis = (const float*)d_in[3];
    const float* W1    = (const float*)d_in[4];
    const float* b1    = (const float*)d_in[5];
    const float* W2    = (const float*)d_in[6];
    const float* b2    = (const float*)d_in[7];
    const float* W3    = (const float*)d_in[8];
    float*       outp  = (float*)d_out;

    dim3 grid(N_EDGES / BLK);   // 3125 blocks, exact — no tail
    pilayer_f32_v3<<<grid, dim3(BLK), 0, stream>>>(prop, idx_i, idx_j, basis,
                                                   W1, b1, W2, b2, W3, outp);
}

// Round 13
// 199.546 us; speedup vs baseline: 23.9758x; 2.2688x over previous
//
#include <hip/hip_runtime.h>

// PILayer v4b: split-fp16 MFMA path (primary) + fp32 fallback if ws_size < 45056.
//   Layer1: X[64 edges,64] @ W1[64,32]   (per wave, 4 M-tiles of 16 edges)
//   Layer2: Y1 @ W2[32,32]
//   Layer3+basis fold: Z[e, k*8+c] = Y2[e,k]*basis[e,c]  (outer product)
//              out = Z[64,256] @ W3'[256,32],  W3'[k*8+c][h] = W3[k][h*8+c]
// Split hi=(f16)v, lo=(f16)(v-hi): 3 MFMAs per product => ~fp32 precision.
// Weights pre-baked into lane-fragment images in d_ws (prep kernel); intra-lane
// k-relabeling cancels because A and B fragments use the same k-labeling.
// Fragment maps (v_mfma_f32_16x16x32_f16): A: row=l&15, k=(l>>4)*8+j;
// B: col=l&15, k=(l>>4)*8+j; C/D: col=l&15, row=(l>>4)*4+reg  [m89-verified].
// All LDS wave-private -> no __syncthreads in the MFMA kernel.

typedef _Float16 half8 __attribute__((ext_vector_type(8)));
typedef float    f32x4 __attribute__((ext_vector_type(4)));

constexpr int N_EDGES = 800000;
constexpr int H       = 32;
constexpr int DOUT    = 256;
constexpr int EPB     = 256;    // edges per block (64 per wave)
constexpr int BLK     = 256;    // 4 waves
constexpr size_t WS_NEED = 22528 * sizeof(_Float16);   // 45056 B

// ---------------------------------------------------------------- prep kernel
__global__ __launch_bounds__(256) void prep_weights(
    const float* __restrict__ W1, const float* __restrict__ W2,
    const float* __restrict__ W3, _Float16* __restrict__ ws)
{
    int idx = blockIdx.x * 256 + threadIdx.x;    // 0..22527 (= 2816*8)
    if (idx >= 22528) return;
    int rem = idx & 511;                          // within-frag: lane*8 + j
    int l  = rem >> 3, jj = rem & 7;
    int gg = l >> 4,   x  = l & 15;
    float val; int f;
    if (idx < 4096) {                             // W1 [64][32]
        f = idx >> 9;                             // 0..7
        int ks = f >> 2, n = (f >> 1) & 1;
        int k  = ks * 32 + gg * 8 + jj;
        val = W1[k * 32 + n * 16 + x];
    } else if (idx < 6144) {                      // W2 [32][32]
        f = (idx - 4096) >> 9;                    // 0..3
        int n = f >> 1;
        int k = gg * 8 + jj;
        val = W2[k * 32 + n * 16 + x];
    } else {                                      // W3 [32][256] -> W3'[kk][h]
        f = (idx - 6144) >> 9;                    // 0..31
        int ks = f >> 2, n = (f >> 1) & 1;
        int kk = ks * 32 + gg * 8 + jj;
        int h  = n * 16 + x;
        val = W3[(kk >> 3) * 256 + h * 8 + (kk & 7)];
    }
    int p = f & 1;
    _Float16 hi = (_Float16)val;
    ws[idx] = p ? (_Float16)(val - (float)hi) : hi;
}

__device__ __forceinline__ f32x4 mfma16(half8 a, half8 b, f32x4 c) {
    return __builtin_amdgcn_mfma_f32_16x16x32_f16(a, b, c, 0, 0, 0);
}

__device__ __forceinline__ void split8(const float* v, half8& hi, half8& lo) {
    #pragma unroll
    for (int q = 0; q < 8; ++q) {
        _Float16 h = (_Float16)v[q];
        hi[q] = h;
        lo[q] = (_Float16)(v[q] - (float)h);
    }
}

// ---------------------------------------------------------------- MFMA kernel
__global__ __launch_bounds__(BLK, 3) void pilayer_mfma(
    const float* __restrict__ prop,  const int* __restrict__ idx_i,
    const int*   __restrict__ idx_j, const float* __restrict__ basis,
    const float* __restrict__ b1v,   const float* __restrict__ b2v,
    const _Float16* __restrict__ ws, float* __restrict__ out)
{
    const int t    = threadIdx.x;
    const int lane = t & 63;
    const int wv   = t >> 6;          // wave 0..3
    const int x    = lane & 15;       // M-row / N-col within tile
    const int g    = lane >> 4;       // k-group 0..3
    const int e0   = blockIdx.x * EPB + wv * 64;   // wave's 64 edges

    // per-wave private LDS: Ybuf [64][36] fp32 (XOR-swizzled) + basis [64][12]
    __shared__ float lds[4 * 3072];   // 49152 B
    float* yb = &lds[wv * 3072];
    float* bb = yb + 64 * 36;

    const float4* prop4  = reinterpret_cast<const float4*>(prop);
    const float4* basis4 = reinterpret_cast<const float4*>(basis);
    const half8*  wsv    = reinterpret_cast<const half8*>(ws);

    // ---- stage basis rows into padded LDS [64][12] (wave-private, no barrier) ----
    #pragma unroll
    for (int r = 0; r < 2; ++r) {
        int i4 = r * 64 + lane;                       // float4 index 0..127
        float4 v = basis4[e0 * 2 + i4];
        *reinterpret_cast<float4*>(&bb[(i4 >> 1) * 12 + (i4 & 1) * 4]) = v;
    }

    // ---- layer 1: acc1 = X @ W1 + b1 ----
    half8 w1f[2][2][2];
    #pragma unroll
    for (int ks = 0; ks < 2; ++ks)
        #pragma unroll
        for (int n = 0; n < 2; ++n)
            #pragma unroll
            for (int p = 0; p < 2; ++p)
                w1f[ks][n][p] = wsv[((ks * 2 + n) * 2 + p) * 64 + lane];

    float bias1[2] = { b1v[x], b1v[16 + x] };
    f32x4 acc1[4][2];
    #pragma unroll
    for (int m = 0; m < 4; ++m)
        #pragma unroll
        for (int n = 0; n < 2; ++n)
            acc1[m][n] = f32x4{bias1[n], bias1[n], bias1[n], bias1[n]};

    int ei[4], ej[4];
    #pragma unroll
    for (int m = 0; m < 4; ++m) {
        int er = e0 + m * 16 + x;
        ei[m] = idx_i[er];
        ej[m] = idx_j[er];
    }

    #pragma unroll
    for (int m = 0; m < 4; ++m) {
        float xv[8];
        half8 ah, al;
        *reinterpret_cast<float4*>(&xv[0]) = prop4[ei[m] * 8 + g * 2];
        *reinterpret_cast<float4*>(&xv[4]) = prop4[ei[m] * 8 + g * 2 + 1];
        split8(xv, ah, al);
        #pragma unroll
        for (int n = 0; n < 2; ++n) {
            acc1[m][n] = mfma16(ah, w1f[0][n][0], acc1[m][n]);
            acc1[m][n] = mfma16(ah, w1f[0][n][1], acc1[m][n]);
            acc1[m][n] = mfma16(al, w1f[0][n][0], acc1[m][n]);
        }
        *reinterpret_cast<float4*>(&xv[0]) = prop4[ej[m] * 8 + g * 2];
        *reinterpret_cast<float4*>(&xv[4]) = prop4[ej[m] * 8 + g * 2 + 1];
        split8(xv, ah, al);
        #pragma unroll
        for (int n = 0; n < 2; ++n) {
            acc1[m][n] = mfma16(ah, w1f[1][n][0], acc1[m][n]);
            acc1[m][n] = mfma16(ah, w1f[1][n][1], acc1[m][n]);
            acc1[m][n] = mfma16(al, w1f[1][n][0], acc1[m][n]);
        }
    }

    // write Y1 -> yb (C-layout scatter), XOR swizzle ch^((row&3)<<3), stride 36
    #pragma unroll
    for (int m = 0; m < 4; ++m)
        #pragma unroll
        for (int n = 0; n < 2; ++n)
            #pragma unroll
            for (int r = 0; r < 4; ++r) {
                int row = m * 16 + g * 4 + r;
                int ch  = n * 16 + x;
                yb[row * 36 + (ch ^ ((row & 3) << 3))] = acc1[m][n][r];
            }

    // ---- layer 2: acc2 = Y1 @ W2 + b2 ----
    half8 w2f[2][2];
    #pragma unroll
    for (int n = 0; n < 2; ++n)
        #pragma unroll
        for (int p = 0; p < 2; ++p)
            w2f[n][p] = wsv[512 + (n * 2 + p) * 64 + lane];

    float bias2[2] = { b2v[x], b2v[16 + x] };
    f32x4 acc2[4][2];
    #pragma unroll
    for (int m = 0; m < 4; ++m)
        #pragma unroll
        for (int n = 0; n < 2; ++n)
            acc2[m][n] = f32x4{bias2[n], bias2[n], bias2[n], bias2[n]};

    #pragma unroll
    for (int m = 0; m < 4; ++m) {
        int row = m * 16 + x;
        int s   = (row & 3) << 3;
        float yv[8];
        *reinterpret_cast<float4*>(&yv[0]) =
            *reinterpret_cast<const float4*>(&yb[row * 36 + ((g * 8) ^ s)]);
        *reinterpret_cast<float4*>(&yv[4]) =
            *reinterpret_cast<const float4*>(&yb[row * 36 + (((g * 8) ^ s) + 4)]);
        half8 ah, al; split8(yv, ah, al);
        #pragma unroll
        for (int n = 0; n < 2; ++n) {
            acc2[m][n] = mfma16(ah, w2f[n][0], acc2[m][n]);
            acc2[m][n] = mfma16(ah, w2f[n][1], acc2[m][n]);
            acc2[m][n] = mfma16(al, w2f[n][0], acc2[m][n]);
        }
    }

    // write Y2 -> yb (same-wave in-order LDS: write->read ordering guaranteed)
    #pragma unroll
    for (int m = 0; m < 4; ++m)
        #pragma unroll
        for (int n = 0; n < 2; ++n)
            #pragma unroll
            for (int r = 0; r < 4; ++r) {
                int row = m * 16 + g * 4 + r;
                int ch  = n * 16 + x;
                yb[row * 36 + (ch ^ ((row & 3) << 3))] = acc2[m][n][r];
            }

    // ---- layer 3: Z = y2 (x) basis, out = Z @ W3' ----
    float bs[4][8];
    #pragma unroll
    for (int m = 0; m < 4; ++m) {
        int row = m * 16 + x;
        *reinterpret_cast<float4*>(&bs[m][0]) = *reinterpret_cast<const float4*>(&bb[row * 12]);
        *reinterpret_cast<float4*>(&bs[m][4]) = *reinterpret_cast<const float4*>(&bb[row * 12 + 4]);
    }

    f32x4 acc3[4][2];
    #pragma unroll
    for (int m = 0; m < 4; ++m)
        #pragma unroll
        for (int n = 0; n < 2; ++n)
            acc3[m][n] = f32x4{0.f, 0.f, 0.f, 0.f};

    #pragma unroll 2
    for (int ks = 0; ks < 8; ++ks) {
        half8 zh[4], zl[4];
        #pragma unroll
        for (int m = 0; m < 4; ++m) {
            int row = m * 16 + x;
            int kq  = ks * 4 + g;                 // Y2 channel for this lane's k-group
            float yv = yb[row * 36 + (kq ^ ((row & 3) << 3))];
            float z[8];
            #pragma unroll
            for (int c = 0; c < 8; ++c) z[c] = yv * bs[m][c];
            split8(z, zh[m], zl[m]);
        }
        #pragma unroll
        for (int n = 0; n < 2; ++n) {
            half8 wh = wsv[768 + ((ks * 2 + n) * 2 + 0) * 64 + lane];
            half8 wl = wsv[768 + ((ks * 2 + n) * 2 + 1) * 64 + lane];
            #pragma unroll
            for (int m = 0; m < 4; ++m) {
                acc3[m][n] = mfma16(zh[m], wh, acc3[m][n]);
                acc3[m][n] = mfma16(zh[m], wl, acc3[m][n]);
                acc3[m][n] = mfma16(zl[m], wh, acc3[m][n]);
            }
        }
    }

    // ---- epilogue: out[edge][ch], 4 edges x 64B dense segments per store ----
    #pragma unroll
    for (int m = 0; m < 4; ++m)
        #pragma unroll
        for (int n = 0; n < 2; ++n)
            #pragma unroll
            for (int r = 0; r < 4; ++r) {
                int edge = e0 + m * 16 + g * 4 + r;
                out[edge * 32 + n * 16 + x] = acc3[m][n][r];
            }
}

// ------------------------------------------------- fp32 fallback (proven v3)
__global__ __launch_bounds__(256, 4) void pilayer_f32_v3(
    const float* __restrict__ prop,
    const int*   __restrict__ idx_i,
    const int*   __restrict__ idx_j,
    const float* __restrict__ basis,
    const float* __restrict__ W1,
    const float* __restrict__ b1,
    const float* __restrict__ W2,
    const float* __restrict__ b2,
    const float* __restrict__ W3,
    float*       __restrict__ out)
{
    const int t  = threadIdx.x;
    const int eb = blockIdx.x * 256;
    const int e  = eb + t;

    __shared__ float4 obuf[256][8];

    const float4* prop4  = reinterpret_cast<const float4*>(prop);
    const float4* basis4 = reinterpret_cast<const float4*>(basis);
    float4*       out4   = reinterpret_cast<float4*>(out);

    const int i = idx_i[e];
    const int j = idx_j[e];
    const float4 bs0 = basis4[e * 2 + 0];
    const float4 bs1 = basis4[e * 2 + 1];

    float4 xi[8], xj[8];
    #pragma unroll
    for (int q = 0; q < 8; ++q) xi[q] = prop4[i * 8 + q];
    #pragma unroll
    for (int q = 0; q < 8; ++q) xj[q] = prop4[j * 8 + q];

    float y1[H];
    #pragma unroll
    for (int m = 0; m < H; ++m) y1[m] = b1[m];
    #pragma unroll
    for (int q = 0; q < 8; ++q) {
        const float* w = W1 + (4 * q) * H;
        #pragma unroll
        for (int m = 0; m < H; ++m) {
            float a = y1[m];
            a = fmaf(xi[q].x, w[0 * H + m], a);
            a = fmaf(xi[q].y, w[1 * H + m], a);
            a = fmaf(xi[q].z, w[2 * H + m], a);
            a = fmaf(xi[q].w, w[3 * H + m], a);
            y1[m] = a;
        }
    }
    #pragma unroll
    for (int q = 0; q < 8; ++q) {
        const float* w = W1 + (32 + 4 * q) * H;
        #pragma unroll
        for (int m = 0; m < H; ++m) {
            float a = y1[m];
            a = fmaf(xj[q].x, w[0 * H + m], a);
            a = fmaf(xj[q].y, w[1 * H + m], a);
            a = fmaf(xj[q].z, w[2 * H + m], a);
            a = fmaf(xj[q].w, w[3 * H + m], a);
            y1[m] = a;
        }
    }

    float y2[H];
    #pragma unroll
    for (int m = 0; m < H; ++m) y2[m] = b2[m];
    #pragma unroll
    for (int k = 0; k < H; ++k) {
        const float yk = y1[k];
        const float* w = W2 + k * H;
        #pragma unroll
        for (int m = 0; m < H; ++m)
            y2[m] = fmaf(yk, w[m], y2[m]);
    }

    #pragma unroll 1
    for (int hq = 0; hq < 8; ++hq) {
        float u[4][8];
        #pragma unroll
        for (int hh = 0; hh < 4; ++hh)
            #pragma unroll
            for (int c = 0; c < 8; ++c) u[hh][c] = 0.f;

        const float* wbase = W3 + hq * 32;
        #pragma unroll
        for (int k = 0; k < H; ++k) {
            const float yk = y2[k];
            const float* w = wbase + k * DOUT;
            #pragma unroll
            for (int hh = 0; hh < 4; ++hh) {
                #pragma unroll
                for (int c = 0; c < 8; ++c)
                    u[hh][c] = fmaf(yk, w[hh * 8 + c], u[hh][c]);
            }
        }

        float4 r;
        #pragma unroll
        for (int hh = 0; hh < 4; ++hh) {
            float a;
            a = u[hh][0] * bs0.x;
            a = fmaf(u[hh][1], bs0.y, a);
            a = fmaf(u[hh][2], bs0.z, a);
            a = fmaf(u[hh][3], bs0.w, a);
            a = fmaf(u[hh][4], bs1.x, a);
            a = fmaf(u[hh][5], bs1.y, a);
            a = fmaf(u[hh][6], bs1.z, a);
            a = fmaf(u[hh][7], bs1.w, a);
            (&r.x)[hh] = a;
        }
        obuf[t][(hq + t) & 7] = r;
    }

    __syncthreads();

    #pragma unroll
    for (int r8 = 0; r8 < 8; ++r8) {
        const int g    = r8 * 256 + t;
        const int eloc = g >> 3;
        const int hq   = g & 7;
        out4[eb * 8 + g] = obuf[eloc][(hq + eloc) & 7];
    }
}

extern "C" void kernel_launch(void* const* d_in, const int* in_sizes, int n_in,
                              void* d_out, int out_size, void* d_ws, size_t ws_size,
                              hipStream_t stream) {
    const float* prop  = (const float*)d_in[0];
    const int*   idx_i = (const int*)d_in[1];
    const int*   idx_j = (const int*)d_in[2];
    const float* basis = (const float*)d_in[3];
    const float* W1    = (const float*)d_in[4];
    const float* b1    = (const float*)d_in[5];
    const float* W2    = (const float*)d_in[6];
    const float* b2    = (const float*)d_in[7];
    const float* W3    = (const float*)d_in[8];
    float*       outp  = (float*)d_out;

    if (ws_size >= WS_NEED && d_ws != nullptr) {
        _Float16* ws = (_Float16*)d_ws;
        prep_weights<<<dim3(88), dim3(256), 0, stream>>>(W1, W2, W3, ws);
        pilayer_mfma<<<dim3(N_EDGES / EPB), dim3(BLK), 0, stream>>>(
            prop, idx_i, idx_j, basis, b1, b2, ws, outp);
    } else {
        pilayer_f32_v3<<<dim3(N_EDGES / 256), dim3(256), 0, stream>>>(
            prop, idx_i, idx_j, basis, W1, b1, W2, b2, W3, outp);
    }
}